// Round 10
// baseline (289.323 us; speedup 1.0000x reference)
//
#include <hip/hip_runtime.h>
#include <math.h>

// B=4, C1=128, C2=256, H=W=64, HW=4096, k=3, N=9
// ws layout (float units):
//   xp   : [4][256][4096] f32  (CHW, for K2)     @ 0          (4194304)
//   off  : [4][18][4096]  f32                    @ 4194304    (294912)
//   xph  : [4][4096][256] bf16 (HWC)             @ 4489216    (2097152 slots)
//   wTb  : [9][256o][256c] bf16                  @ 6586368    (294912 slots)
//   part : [8][4][18][4096] f32                  @ 6881280    (2359296)
//   samp : [4][9][128 tile][8192] bf16 swizzled  @ 9240576    (18874368 slots)
#define XP_F   0
#define OFF_F  4194304
#define XPH_F  4489216
#define WTB_F  6586368
#define PART_F 6881280
#define SAMP_F 9240576
#define SPLIT_END_F 28114944ULL   // SAMP_F + 18874368

typedef short bf16x8 __attribute__((ext_vector_type(8)));
typedef float f32x4 __attribute__((ext_vector_type(4)));

__device__ inline unsigned short f2b(float f) {
    union { float f; unsigned u; } v; v.f = f;
    unsigned r = v.u + 0x7FFF + ((v.u >> 16) & 1);   // RNE
    return (unsigned short)(r >> 16);
}
__device__ inline float b2f(unsigned short h) {
    union { unsigned u; float f; } v; v.u = ((unsigned)h) << 16; return v.f;
}

// ---------------------------------------------------------------------------
// K0: wTb[n][o][c] = bf16(dcn[o][c][n]). grid 2304 x 256
__global__ __launch_bounds__(256) void k0_prep(const float* __restrict__ dcn,
                                               unsigned short* __restrict__ wTb) {
    int idx = blockIdx.x * 256 + threadIdx.x;
    int n = idx >> 16, o = (idx >> 8) & 255, c = idx & 255;
    wTb[idx] = f2b(dcn[(o * 256 + c) * 9 + n]);
}

// ---------------------------------------------------------------------------
// K1: pointwise conv (128->256) + BN; writes xp (f32 CHW) and xph (bf16 HWC).
__global__ __launch_bounds__(256, 4) void k1_pw_bn(const float* __restrict__ x,
                                                   const float* __restrict__ pw,
                                                   const float* __restrict__ gamma,
                                                   const float* __restrict__ beta,
                                                   const float* __restrict__ mean,
                                                   const float* __restrict__ var,
                                                   float* __restrict__ xp,
                                                   unsigned short* __restrict__ xph) {
    __shared__ float wl[128 * 64];
    int t = threadIdx.x;
    int m0 = blockIdx.x * 64;
    int b = m0 >> 12;
    int hw = (m0 & 4095) + (t & 63);
    int q = t >> 6;
    int c2base = blockIdx.y * 64;

    for (int i = 0; i < 32; ++i) {
        int idx = t + 256 * i;
        int kk = idx >> 6, c2l = idx & 63;
        wl[idx] = pw[(c2base + c2l) * 128 + kk];
    }
    __syncthreads();

    float acc[16];
#pragma unroll
    for (int i = 0; i < 16; ++i) acc[i] = 0.f;

    const float* xb = x + (b * 128) * 4096 + hw;
    for (int kk = 0; kk < 128; kk += 8) {
        float xv[8];
#pragma unroll
        for (int u = 0; u < 8; ++u) xv[u] = xb[(kk + u) * 4096];
#pragma unroll
        for (int u = 0; u < 8; ++u) {
            const float4* w4 = (const float4*)&wl[(kk + u) * 64 + q * 16];
#pragma unroll
            for (int i = 0; i < 4; ++i) {
                float4 wv = w4[i];
                acc[i * 4 + 0] += xv[u] * wv.x;
                acc[i * 4 + 1] += xv[u] * wv.y;
                acc[i * 4 + 2] += xv[u] * wv.z;
                acc[i * 4 + 3] += xv[u] * wv.w;
            }
        }
    }
    bf16x8 r0, r1;
#pragma unroll
    for (int i = 0; i < 16; ++i) {
        int c2 = c2base + q * 16 + i;
        float s = gamma[c2] * rsqrtf(var[c2] + 1e-5f);
        float v = acc[i] * s + (beta[c2] - mean[c2] * s);
        xp[((b * 256 + c2) << 12) + hw] = v;
        if (i < 8) r0[i] = (short)f2b(v); else r1[i - 8] = (short)f2b(v);
    }
    unsigned short* hb = xph + (((b << 12) + hw) << 8) + c2base + q * 16;
    *(bf16x8*)hb = r0;
    *(bf16x8*)(hb + 8) = r1;
}

// ---------------------------------------------------------------------------
// K2a: 3x3 offset conv (256 -> 18) partial sums, NO atomics. grid 2048 x 256
__global__ __launch_bounds__(256) void k2a_off(const float* __restrict__ xp,
                                               const float* __restrict__ offw,
                                               float* __restrict__ part) {
    __shared__ float xl[3 * 32 * 66];
    __shared__ float wl[9 * 18 * 32];
    int t = threadIdx.x;
    int bx = blockIdx.x;
    int b = bx >> 9, h = (bx >> 3) & 63, cs = bx & 7;
    int w = t & 63, jset = t >> 6;
    const int jbase_a[4] = {0, 5, 10, 14};
    const int jcnt_a[4] = {5, 5, 4, 4};
    int jbase = jbase_a[jset], jcnt = jcnt_a[jset];
    float acc[5] = {0.f, 0.f, 0.f, 0.f, 0.f};
    int cbase = cs * 32;

    for (int idx = t; idx < 3 * 32 * 66; idx += 256) {
        int dy = idx / 2112, rem = idx % 2112;
        int c = rem / 66, col = rem % 66;
        int y = h + dy - 1, wc = col - 1;
        float v = 0.f;
        if ((unsigned)y < 64u && (unsigned)wc < 64u)
            v = xp[((b * 256 + cbase + c) << 12) + y * 64 + wc];
        xl[idx] = v;
    }
    for (int idx = t; idx < 18 * 32 * 9; idx += 256) {
        int j = idx / 288, c = (idx / 9) % 32, tap = idx % 9;
        wl[(tap * 18 + j) * 32 + c] = offw[(j * 256 + cbase + c) * 9 + tap];
    }
    __syncthreads();
#pragma unroll
    for (int tap = 0; tap < 9; ++tap) {
        int dy = tap / 3, dx = tap % 3;
        const float* xrow = &xl[dy * 2112 + (w + dx)];
        const float4* wrow = (const float4*)&wl[(tap * 18 + jbase) * 32];
#pragma unroll
        for (int c4 = 0; c4 < 8; ++c4) {
            float xv0 = xrow[(c4 * 4 + 0) * 66];
            float xv1 = xrow[(c4 * 4 + 1) * 66];
            float xv2 = xrow[(c4 * 4 + 2) * 66];
            float xv3 = xrow[(c4 * 4 + 3) * 66];
#pragma unroll
            for (int jj = 0; jj < 5; ++jj) {
                if (jj < jcnt) {
                    float4 wv = wrow[jj * 8 + c4];
                    acc[jj] += xv0 * wv.x + xv1 * wv.y + xv2 * wv.z + xv3 * wv.w;
                }
            }
        }
    }
    for (int jj = 0; jj < 5; ++jj) {
        if (jj < jcnt)
            part[(((cs * 4 + b) * 18 + jbase + jj) << 12) + h * 64 + w] = acc[jj];
    }
}

// K2b: off = bias + sum_cs part. grid 1152 x 256
__global__ __launch_bounds__(256) void k2b_red(const float* __restrict__ part,
                                               const float* __restrict__ offb,
                                               float* __restrict__ off) {
    int i = blockIdx.x * 256 + threadIdx.x;
    int j = (i >> 12) % 18;
    float s = offb[j];
#pragma unroll
    for (int cs = 0; cs < 8; ++cs) s += part[cs * 294912 + i];
    off[i] = s;
}

// ---------------------------------------------------------------------------
// K3a: deformable bilinear sampler -> samp in MFMA-fragment-swizzled layout.
// grid 4608 = (b*9+tap)*128 + pb, pb = h*2+half. 256 thr, 4 units each.
// Unit u = F*64+chunk; data = (px = (F>>3)*16 + ((chunk^(F&7))&15),
//                              cg = (F&7)*4 + (chunk>>4)).
// Stores are wave-linear (1KB/wave); gathers are 16x64B segments (L2).
__global__ __launch_bounds__(256) void k3a_samp(const unsigned short* __restrict__ xph,
                                                const float* __restrict__ off,
                                                unsigned short* __restrict__ samp) {
    __shared__ int   c00[32], c01[32], c10[32], c11[32];
    __shared__ float4 wts[32];
    int t = threadIdx.x;
    int bid = blockIdx.x;
    int b = bid / 1152, r = bid % 1152;
    int tap = r >> 7, pb = r & 127;
    int h = pb >> 1, wh = (pb & 1) * 32;

    if (t < 32) {
        int w = wh + t;
        int hw = h * 64 + w;
        float oy = off[((b * 18 + tap) << 12) + hw];
        float ox = off[((b * 18 + tap + 9) << 12) + hw];
        float py = (float)(h + tap / 3 - 1) + oy;
        float px = (float)(w + tap % 3 - 1) + ox;
        py = fminf(fmaxf(py, 0.f), 63.f);
        px = fminf(fmaxf(px, 0.f), 63.f);
        float fy = floorf(py), fx = floorf(px);
        int y0 = (int)fy, x0 = (int)fx;
        float wy = py - fy, wx = px - fx;
        int y1 = min(y0 + 1, 63), x1 = min(x0 + 1, 63);
        c00[t] = (y0 * 64 + x0) << 8;  c01[t] = (y0 * 64 + x1) << 8;
        c10[t] = (y1 * 64 + x0) << 8;  c11[t] = (y1 * 64 + x1) << 8;
        wts[t] = make_float4((1.f - wy) * (1.f - wx), (1.f - wy) * wx,
                             wy * (1.f - wx), wy * wx);
    }
    __syncthreads();

    const unsigned short* xb = xph + (b << 20);
    unsigned short* sb = samp + bid * 8192;
#pragma unroll
    for (int i = 0; i < 4; ++i) {
        int u = i * 256 + t;
        int F = u >> 6, chunk = u & 63;
        int lane = chunk ^ (F & 7);
        int pxl = (F >> 3) * 16 + (lane & 15);
        int co = ((F & 7) * 4 + (lane >> 4)) << 3;
        float4 wv = wts[pxl];
        bf16x8 v00 = *(const bf16x8*)(xb + c00[pxl] + co);
        bf16x8 v01 = *(const bf16x8*)(xb + c01[pxl] + co);
        bf16x8 v10 = *(const bf16x8*)(xb + c10[pxl] + co);
        bf16x8 v11 = *(const bf16x8*)(xb + c11[pxl] + co);
        bf16x8 rr;
#pragma unroll
        for (int j = 0; j < 8; ++j) {
            float v = wv.x * b2f((unsigned short)v00[j]) +
                      wv.y * b2f((unsigned short)v01[j]) +
                      wv.z * b2f((unsigned short)v10[j]) +
                      wv.w * b2f((unsigned short)v11[j]);
            rr[j] = (short)f2b(v);
        }
        *(bf16x8*)(sb + (u << 3)) = rr;
    }
}

// ---------------------------------------------------------------------------
// K3b: regular GEMM over samp tiles (contiguous 16KB per tap) + SiLU.
// 512 thr = 8 waves; tile 32px x 256o; global_load_lds double-buffered.
__global__ __launch_bounds__(512, 4) void k3b_gemm(const unsigned short* __restrict__ samp,
                                                   const unsigned short* __restrict__ wTb,
                                                   float* __restrict__ out) {
    __shared__ unsigned short smp[2][8192];      // 16KB per buffer
    int t = threadIdx.x;
    int orig = blockIdx.x;
    int bx = (orig & 7) * 64 + (orig >> 3);      // XCD-bijective (512%8==0)
    int b = bx >> 7, h = (bx >> 1) & 63, half = bx & 1, wh = half * 32;
    int wv = t >> 6, l = t & 63;
    int tile0 = (b * 9) * 128 + h * 2 + half;    // + tap*128

    auto stage = [&](int tap) {
        const unsigned short* src = samp + (tile0 + tap * 128) * 8192 + t * 8;
        unsigned short* dst = &smp[tap & 1][t * 8];
#if __has_builtin(__builtin_amdgcn_global_load_lds)
        __builtin_amdgcn_global_load_lds(
            (const __attribute__((address_space(1))) unsigned int*)src,
            (__attribute__((address_space(3))) unsigned int*)dst, 16, 0, 0);
        __builtin_amdgcn_global_load_lds(
            (const __attribute__((address_space(1))) unsigned int*)(src + 4096),
            (__attribute__((address_space(3))) unsigned int*)(dst + 4096), 16, 0, 0);
#else
        *(bf16x8*)dst = *(const bf16x8*)src;
        *(bf16x8*)(dst + 4096) = *(const bf16x8*)(src + 4096);
#endif
    };

    stage(0);
    __syncthreads();                              // drains vmcnt before barrier

    f32x4 acc[2][2];
#pragma unroll
    for (int i = 0; i < 2; ++i)
#pragma unroll
        for (int j = 0; j < 2; ++j) acc[i][j] = (f32x4)0.f;

    int arow = l & 15, areg = l >> 4;
    for (int tap = 0; tap < 9; ++tap) {
        if (tap < 8) stage(tap + 1);              // async into buf^1
        int bu = tap & 1;
        const unsigned short* wbase =
            wTb + (tap * 256 + wv * 32 + arow) * 256 + areg * 8;
        __builtin_amdgcn_s_setprio(1);
#pragma unroll
        for (int ks = 0; ks < 8; ++ks) {
            bf16x8 a0 = *(const bf16x8*)(wbase + ks * 32);
            bf16x8 a1 = *(const bf16x8*)(wbase + 16 * 256 + ks * 32);
#pragma unroll
            for (int pt = 0; pt < 2; ++pt) {
                int F = pt * 8 + ks;
                bf16x8 bfr = *(const bf16x8*)
                    &smp[bu][(F * 64 + (l ^ (F & 7))) << 3];
                acc[0][pt] = __builtin_amdgcn_mfma_f32_16x16x32_bf16(a0, bfr, acc[0][pt], 0, 0, 0);
                acc[1][pt] = __builtin_amdgcn_mfma_f32_16x16x32_bf16(a1, bfr, acc[1][pt], 0, 0, 0);
            }
        }
        __builtin_amdgcn_s_setprio(0);
        __syncthreads();                          // stage(tap+1) landed
    }

#pragma unroll
    for (int ot = 0; ot < 2; ++ot)
#pragma unroll
        for (int pt = 0; pt < 2; ++pt) {
            int px = wh + pt * 16 + (l & 15);
#pragma unroll
            for (int j = 0; j < 4; ++j) {
                int o = wv * 32 + ot * 16 + (l >> 4) * 4 + j;
                float a = acc[ot][pt][j];
                out[((b * 256 + o) << 12) + h * 64 + px] = a / (1.f + expf(-a));
            }
        }
}

// ---------------------------------------------------------------------------
// K3 fused fallback (round-9 kernel) — used only if ws too small for samp.
__global__ __launch_bounds__(512, 4) void k3_dcn(const unsigned short* __restrict__ xph,
                                                 const float* __restrict__ off,
                                                 const unsigned short* __restrict__ wTb,
                                                 float* __restrict__ out) {
    __shared__ int   i00[288], i01[288], i10[288], i11[288];
    __shared__ float w00[288], w01[288], w10[288], w11[288];
    __shared__ unsigned short smp[2][16 * 64 * 8];
    int t = threadIdx.x;
    int orig = blockIdx.x;
    int bx = (orig & 7) * 64 + (orig >> 3);
    int b = bx >> 7, h = (bx >> 1) & 63, wh = (bx & 1) * 32;
    int wv = t >> 6, l = t & 63;
    const unsigned short* xb = xph + (b << 20);

    if (t < 288) {
        int n = t >> 5, p = t & 31;
        int w = wh + p;
        float oy = off[((b * 18 + n) << 12) + h * 64 + w];
        float ox = off[((b * 18 + n + 9) << 12) + h * 64 + w];
        float py = (float)(h + n / 3 - 1) + oy;
        float px = (float)(w + n % 3 - 1) + ox;
        py = fminf(fmaxf(py, 0.f), 63.f);
        px = fminf(fmaxf(px, 0.f), 63.f);
        float fy = floorf(py), fx = floorf(px);
        int y0 = (int)fy, x0 = (int)fx;
        float wy = py - fy, wx = px - fx;
        int y1 = min(y0 + 1, 63), x1 = min(x0 + 1, 63);
        i00[t] = (y0 * 64 + x0) << 8;  i01[t] = (y0 * 64 + x1) << 8;
        i10[t] = (y1 * 64 + x0) << 8;  i11[t] = (y1 * 64 + x1) << 8;
        w00[t] = (1.f - wy) * (1.f - wx);  w01[t] = (1.f - wy) * wx;
        w10[t] = wy * (1.f - wx);          w11[t] = wy * wx;
    }
    __syncthreads();

    int pt_p = wv & 1;
    int ks0 = wv >> 1;
    int px_p = pt_p * 16 + (l & 15);
    int cgl = l >> 4;
    bf16x8 g[2][4];

    auto stage_issue = [&](int tap) {
        int sb = tap * 32 + px_p;
        int a00 = i00[sb], a01 = i01[sb], a10 = i10[sb], a11 = i11[sb];
#pragma unroll
        for (int ku = 0; ku < 2; ++ku) {
            int ks = ks0 + ku * 4;
            int c = (ks * 4 + cgl) << 3;
            g[ku][0] = *(const bf16x8*)(xb + a00 + c);
            g[ku][1] = *(const bf16x8*)(xb + a01 + c);
            g[ku][2] = *(const bf16x8*)(xb + a10 + c);
            g[ku][3] = *(const bf16x8*)(xb + a11 + c);
        }
    };
    auto stage_write = [&](int tap) {
        int bu = tap & 1;
        int sb = tap * 32 + px_p;
        float b00 = w00[sb], b01 = w01[sb], b10 = w10[sb], b11 = w11[sb];
#pragma unroll
        for (int ku = 0; ku < 2; ++ku) {
            bf16x8 r;
#pragma unroll
            for (int j = 0; j < 8; ++j) {
                float v = b00 * b2f((unsigned short)g[ku][0][j]) +
                          b01 * b2f((unsigned short)g[ku][1][j]) +
                          b10 * b2f((unsigned short)g[ku][2][j]) +
                          b11 * b2f((unsigned short)g[ku][3][j]);
                r[j] = (short)f2b(v);
            }
            int F = pt_p * 8 + ks0 + ku * 4;
            *(bf16x8*)&smp[bu][(F * 64 + (l ^ (F & 7))) << 3] = r;
        }
    };

    stage_issue(0);
    __builtin_amdgcn_sched_barrier(0);
    stage_write(0);
    __syncthreads();

    f32x4 acc[2][2];
#pragma unroll
    for (int i = 0; i < 2; ++i)
#pragma unroll
        for (int j = 0; j < 2; ++j) acc[i][j] = (f32x4)0.f;

    int arow = l & 15, areg = l >> 4;
    for (int tap = 0; tap < 9; ++tap) {
        if (tap < 8) stage_issue(tap + 1);
        __builtin_amdgcn_sched_barrier(0);
        int bu = tap & 1;
        const unsigned short* wbase =
            wTb + (tap * 256 + wv * 32 + arow) * 256 + areg * 8;
        __builtin_amdgcn_s_setprio(1);
#pragma unroll
        for (int ks = 0; ks < 8; ++ks) {
            bf16x8 a0 = *(const bf16x8*)(wbase + ks * 32);
            bf16x8 a1 = *(const bf16x8*)(wbase + 16 * 256 + ks * 32);
#pragma unroll
            for (int pt = 0; pt < 2; ++pt) {
                int F = pt * 8 + ks;
                bf16x8 bfr = *(const bf16x8*)
                    &smp[bu][(F * 64 + (l ^ (F & 7))) << 3];
                acc[0][pt] = __builtin_amdgcn_mfma_f32_16x16x32_bf16(a0, bfr, acc[0][pt], 0, 0, 0);
                acc[1][pt] = __builtin_amdgcn_mfma_f32_16x16x32_bf16(a1, bfr, acc[1][pt], 0, 0, 0);
            }
        }
        __builtin_amdgcn_s_setprio(0);
        __builtin_amdgcn_sched_barrier(0);
        if (tap < 8) stage_write(tap + 1);
        __syncthreads();
    }

#pragma unroll
    for (int ot = 0; ot < 2; ++ot)
#pragma unroll
        for (int pt = 0; pt < 2; ++pt) {
            int px = wh + pt * 16 + (l & 15);
#pragma unroll
            for (int j = 0; j < 4; ++j) {
                int o = wv * 32 + ot * 16 + (l >> 4) * 4 + j;
                float a = acc[ot][pt][j];
                out[((b * 256 + o) << 12) + h * 64 + px] = a / (1.f + expf(-a));
            }
        }
}

// ---------------------------------------------------------------------------
extern "C" void kernel_launch(void* const* d_in, const int* in_sizes, int n_in,
                              void* d_out, int out_size, void* d_ws, size_t ws_size,
                              hipStream_t stream) {
    const float* x     = (const float*)d_in[0];
    const float* pw    = (const float*)d_in[1];
    const float* gamma = (const float*)d_in[2];
    const float* beta  = (const float*)d_in[3];
    const float* mean  = (const float*)d_in[4];
    const float* var   = (const float*)d_in[5];
    const float* offw  = (const float*)d_in[6];
    const float* offb  = (const float*)d_in[7];
    const float* dcn   = (const float*)d_in[8];
    float* ws = (float*)d_ws;
    float* xp   = ws + XP_F;
    float* off  = ws + OFF_F;
    unsigned short* xph = (unsigned short*)(ws + XPH_F);
    unsigned short* wTb = (unsigned short*)(ws + WTB_F);
    float* part = ws + PART_F;
    unsigned short* samp = (unsigned short*)(ws + SAMP_F);
    float* out = (float*)d_out;

    hipLaunchKernelGGL(k0_prep, dim3(2304), dim3(256), 0, stream, dcn, wTb);
    hipLaunchKernelGGL(k1_pw_bn, dim3(256, 4), dim3(256), 0, stream,
                       x, pw, gamma, beta, mean, var, xp, xph);
    hipLaunchKernelGGL(k2a_off, dim3(2048), dim3(256), 0, stream, xp, offw, part);
    hipLaunchKernelGGL(k2b_red, dim3(1152), dim3(256), 0, stream, part, offb, off);
    if (ws_size >= SPLIT_END_F * 4ULL) {
        hipLaunchKernelGGL(k3a_samp, dim3(4608), dim3(256), 0, stream, xph, off, samp);
        hipLaunchKernelGGL(k3b_gemm, dim3(512), dim3(512), 0, stream, samp, wTb, out);
    } else {
        hipLaunchKernelGGL(k3_dcn, dim3(512), dim3(512), 0, stream, xph, off, wTb, out);
    }
}

// Round 13
// 252.682 us; speedup vs baseline: 1.1450x; 1.1450x over previous
//
#include <hip/hip_runtime.h>
#include <math.h>

// B=4, C1=128, C2=256, H=W=64, HW=4096, k=3, N=9
// ws layout (float units):
//   xp   : [4][256][4096] f32  (CHW, for K2)     @ 0          (4194304)
//   off  : [4][18][4096]  f32                    @ 4194304    (294912)
//   xph  : [4][4096][256] bf16 (HWC)             @ 4489216    (2097152 slots)
//   wTb  : [9][256o][256c] bf16                  @ 6586368    (294912 slots)
//   part : [8][4][18][4096] f32                  @ 6881280    (2359296)
//   samp : [4][9][128 tile][8192] bf16 swizzled  @ 9240576    (18874368 slots)
#define XP_F   0
#define OFF_F  4194304
#define XPH_F  4489216
#define WTB_F  6586368
#define PART_F 6881280
#define SAMP_F 9240576
#define SPLIT_END_F 28114944ULL   // SAMP_F + 18874368

typedef short bf16x8 __attribute__((ext_vector_type(8)));
typedef float f32x4 __attribute__((ext_vector_type(4)));

__device__ inline unsigned short f2b(float f) {
    union { float f; unsigned u; } v; v.f = f;
    unsigned r = v.u + 0x7FFF + ((v.u >> 16) & 1);   // RNE
    return (unsigned short)(r >> 16);
}
__device__ inline float b2f(unsigned short h) {
    union { unsigned u; float f; } v; v.u = ((unsigned)h) << 16; return v.f;
}

// ---------------------------------------------------------------------------
// K0: wTb[n][o][c] = bf16(dcn[o][c][n]). grid 2304 x 256
__global__ __launch_bounds__(256) void k0_prep(const float* __restrict__ dcn,
                                               unsigned short* __restrict__ wTb) {
    int idx = blockIdx.x * 256 + threadIdx.x;
    int n = idx >> 16, o = (idx >> 8) & 255, c = idx & 255;
    wTb[idx] = f2b(dcn[(o * 256 + c) * 9 + n]);
}

// ---------------------------------------------------------------------------
// K1: pointwise conv (128->256) + BN; writes xp (f32 CHW) and xph (bf16 HWC).
__global__ __launch_bounds__(256, 4) void k1_pw_bn(const float* __restrict__ x,
                                                   const float* __restrict__ pw,
                                                   const float* __restrict__ gamma,
                                                   const float* __restrict__ beta,
                                                   const float* __restrict__ mean,
                                                   const float* __restrict__ var,
                                                   float* __restrict__ xp,
                                                   unsigned short* __restrict__ xph) {
    __shared__ float wl[128 * 64];
    int t = threadIdx.x;
    int m0 = blockIdx.x * 64;
    int b = m0 >> 12;
    int hw = (m0 & 4095) + (t & 63);
    int q = t >> 6;
    int c2base = blockIdx.y * 64;

    for (int i = 0; i < 32; ++i) {
        int idx = t + 256 * i;
        int kk = idx >> 6, c2l = idx & 63;
        wl[idx] = pw[(c2base + c2l) * 128 + kk];
    }
    __syncthreads();

    float acc[16];
#pragma unroll
    for (int i = 0; i < 16; ++i) acc[i] = 0.f;

    const float* xb = x + (b * 128) * 4096 + hw;
    for (int kk = 0; kk < 128; kk += 8) {
        float xv[8];
#pragma unroll
        for (int u = 0; u < 8; ++u) xv[u] = xb[(kk + u) * 4096];
#pragma unroll
        for (int u = 0; u < 8; ++u) {
            const float4* w4 = (const float4*)&wl[(kk + u) * 64 + q * 16];
#pragma unroll
            for (int i = 0; i < 4; ++i) {
                float4 wv = w4[i];
                acc[i * 4 + 0] += xv[u] * wv.x;
                acc[i * 4 + 1] += xv[u] * wv.y;
                acc[i * 4 + 2] += xv[u] * wv.z;
                acc[i * 4 + 3] += xv[u] * wv.w;
            }
        }
    }
    bf16x8 r0, r1;
#pragma unroll
    for (int i = 0; i < 16; ++i) {
        int c2 = c2base + q * 16 + i;
        float s = gamma[c2] * rsqrtf(var[c2] + 1e-5f);
        float v = acc[i] * s + (beta[c2] - mean[c2] * s);
        xp[((b * 256 + c2) << 12) + hw] = v;
        if (i < 8) r0[i] = (short)f2b(v); else r1[i - 8] = (short)f2b(v);
    }
    unsigned short* hb = xph + (((b << 12) + hw) << 8) + c2base + q * 16;
    *(bf16x8*)hb = r0;
    *(bf16x8*)(hb + 8) = r1;
}

// ---------------------------------------------------------------------------
// K2a: 3x3 offset conv (256 -> 18) partial sums, NO atomics. grid 2048 x 256
__global__ __launch_bounds__(256) void k2a_off(const float* __restrict__ xp,
                                               const float* __restrict__ offw,
                                               float* __restrict__ part) {
    __shared__ float xl[3 * 32 * 66];
    __shared__ float wl[9 * 18 * 32];
    int t = threadIdx.x;
    int bx = blockIdx.x;
    int b = bx >> 9, h = (bx >> 3) & 63, cs = bx & 7;
    int w = t & 63, jset = t >> 6;
    const int jbase_a[4] = {0, 5, 10, 14};
    const int jcnt_a[4] = {5, 5, 4, 4};
    int jbase = jbase_a[jset], jcnt = jcnt_a[jset];
    float acc[5] = {0.f, 0.f, 0.f, 0.f, 0.f};
    int cbase = cs * 32;

    for (int idx = t; idx < 3 * 32 * 66; idx += 256) {
        int dy = idx / 2112, rem = idx % 2112;
        int c = rem / 66, col = rem % 66;
        int y = h + dy - 1, wc = col - 1;
        float v = 0.f;
        if ((unsigned)y < 64u && (unsigned)wc < 64u)
            v = xp[((b * 256 + cbase + c) << 12) + y * 64 + wc];
        xl[idx] = v;
    }
    for (int idx = t; idx < 18 * 32 * 9; idx += 256) {
        int j = idx / 288, c = (idx / 9) % 32, tap = idx % 9;
        wl[(tap * 18 + j) * 32 + c] = offw[(j * 256 + cbase + c) * 9 + tap];
    }
    __syncthreads();
#pragma unroll
    for (int tap = 0; tap < 9; ++tap) {
        int dy = tap / 3, dx = tap % 3;
        const float* xrow = &xl[dy * 2112 + (w + dx)];
        const float4* wrow = (const float4*)&wl[(tap * 18 + jbase) * 32];
#pragma unroll
        for (int c4 = 0; c4 < 8; ++c4) {
            float xv0 = xrow[(c4 * 4 + 0) * 66];
            float xv1 = xrow[(c4 * 4 + 1) * 66];
            float xv2 = xrow[(c4 * 4 + 2) * 66];
            float xv3 = xrow[(c4 * 4 + 3) * 66];
#pragma unroll
            for (int jj = 0; jj < 5; ++jj) {
                if (jj < jcnt) {
                    float4 wv = wrow[jj * 8 + c4];
                    acc[jj] += xv0 * wv.x + xv1 * wv.y + xv2 * wv.z + xv3 * wv.w;
                }
            }
        }
    }
    for (int jj = 0; jj < 5; ++jj) {
        if (jj < jcnt)
            part[(((cs * 4 + b) * 18 + jbase + jj) << 12) + h * 64 + w] = acc[jj];
    }
}

// K2b: off = bias + sum_cs part. grid 1152 x 256
__global__ __launch_bounds__(256) void k2b_red(const float* __restrict__ part,
                                               const float* __restrict__ offb,
                                               float* __restrict__ off) {
    int i = blockIdx.x * 256 + threadIdx.x;
    int j = (i >> 12) % 18;
    float s = offb[j];
#pragma unroll
    for (int cs = 0; cs < 8; ++cs) s += part[cs * 294912 + i];
    off[i] = s;
}

// ---------------------------------------------------------------------------
// K3a: deformable bilinear sampler -> samp in MFMA-fragment-swizzled layout.
// grid 4608 = (b*9+tap)*128 + pb, pb = h*2+half. 256 thr, 4 units each.
__global__ __launch_bounds__(256) void k3a_samp(const unsigned short* __restrict__ xph,
                                                const float* __restrict__ off,
                                                unsigned short* __restrict__ samp) {
    __shared__ int   c00[32], c01[32], c10[32], c11[32];
    __shared__ float4 wts[32];
    int t = threadIdx.x;
    int bid = blockIdx.x;
    int b = bid / 1152, r = bid % 1152;
    int tap = r >> 7, pb = r & 127;
    int h = pb >> 1, wh = (pb & 1) * 32;

    if (t < 32) {
        int w = wh + t;
        int hw = h * 64 + w;
        float oy = off[((b * 18 + tap) << 12) + hw];
        float ox = off[((b * 18 + tap + 9) << 12) + hw];
        float py = (float)(h + tap / 3 - 1) + oy;
        float px = (float)(w + tap % 3 - 1) + ox;
        py = fminf(fmaxf(py, 0.f), 63.f);
        px = fminf(fmaxf(px, 0.f), 63.f);
        float fy = floorf(py), fx = floorf(px);
        int y0 = (int)fy, x0 = (int)fx;
        float wy = py - fy, wx = px - fx;
        int y1 = min(y0 + 1, 63), x1 = min(x0 + 1, 63);
        c00[t] = (y0 * 64 + x0) << 8;  c01[t] = (y0 * 64 + x1) << 8;
        c10[t] = (y1 * 64 + x0) << 8;  c11[t] = (y1 * 64 + x1) << 8;
        wts[t] = make_float4((1.f - wy) * (1.f - wx), (1.f - wy) * wx,
                             wy * (1.f - wx), wy * wx);
    }
    __syncthreads();

    const unsigned short* xb = xph + (b << 20);
    unsigned short* sb = samp + bid * 8192;
#pragma unroll
    for (int i = 0; i < 4; ++i) {
        int u = i * 256 + t;
        int F = u >> 6, chunk = u & 63;
        int lane = chunk ^ (F & 7);
        int pxl = (F >> 3) * 16 + (lane & 15);
        int co = ((F & 7) * 4 + (lane >> 4)) << 3;
        float4 wv = wts[pxl];
        bf16x8 v00 = *(const bf16x8*)(xb + c00[pxl] + co);
        bf16x8 v01 = *(const bf16x8*)(xb + c01[pxl] + co);
        bf16x8 v10 = *(const bf16x8*)(xb + c10[pxl] + co);
        bf16x8 v11 = *(const bf16x8*)(xb + c11[pxl] + co);
        bf16x8 rr;
#pragma unroll
        for (int j = 0; j < 8; ++j) {
            float v = wv.x * b2f((unsigned short)v00[j]) +
                      wv.y * b2f((unsigned short)v01[j]) +
                      wv.z * b2f((unsigned short)v10[j]) +
                      wv.w * b2f((unsigned short)v11[j]);
            rr[j] = (short)f2b(v);
        }
        *(bf16x8*)(sb + (u << 3)) = rr;
    }
}

// ---------------------------------------------------------------------------
// K3b v2: GEMM 256o x 64px per block, K=2304 in 36 steps of 64c.
// 1024 thr = 16 waves (8 o-groups x 2 px-halves); wave tile 32o x 32px.
// A (wTb) staged via global_load_lds, dbuf 2x32KB, pre-swizzled source +
// chunk^(row&7) read (rule-21). B (samp, fragment-swizzled) staged per-tap
// dbuf 2x32KB linear. LDS 128KB, grid 256 = 1 block/CU, 4 waves/SIMD.
__global__ __launch_bounds__(1024, 4) void k3b_gemm(const unsigned short* __restrict__ samp,
                                                    const unsigned short* __restrict__ wTb,
                                                    float* __restrict__ out) {
    __shared__ unsigned short ldsA[2][16384];    // [256r][8 chunks of 8 bf16]
    __shared__ unsigned short ldsB[2][16384];    // two 32px fragment tiles
    int t = threadIdx.x;
    int orig = blockIdx.x;
    int bx = (orig & 7) * 32 + (orig >> 3);      // XCD-bijective (256%8==0)
    int b = bx >> 6, hh = bx & 63;
    int wv = t >> 6, l = t & 63;
    int ow = wv >> 1, pxh = wv & 1;
    int tile0 = (b * 9) * 128 + hh * 2;          // + tap*128 (+pxh)

    // A-stage: rows 0..255 x 64c window (ksub*64), source pre-swizzled so
    // linear LDS + XOR read is conflict-free.
    auto stageA = [&](int tap, int ksub, int buf) {
        const unsigned short* base = wTb + tap * 65536 + ksub * 64;
#pragma unroll
        for (int k = 0; k < 2; ++k) {
            int u = t + k * 1024;
            int r = u >> 3, c = u & 7;
            const unsigned short* src = base + r * 256 + ((c ^ (r & 7)) << 3);
            unsigned short* dst = &ldsA[buf][u << 3];
#if __has_builtin(__builtin_amdgcn_global_load_lds)
            __builtin_amdgcn_global_load_lds(
                (const __attribute__((address_space(1))) unsigned int*)src,
                (__attribute__((address_space(3))) unsigned int*)dst, 16, 0, 0);
#else
            *(bf16x8*)dst = *(const bf16x8*)src;
#endif
        }
    };
    // B-stage: one tap = two adjacent 32px tiles, 32KB contiguous.
    auto stageB = [&](int tap, int buf) {
        const unsigned short* sb = samp + (size_t)(tile0 + tap * 128) * 8192;
#pragma unroll
        for (int k = 0; k < 2; ++k) {
            int u = t + k * 1024;
            const unsigned short* src = sb + (u << 3);
            unsigned short* dst = &ldsB[buf][u << 3];
#if __has_builtin(__builtin_amdgcn_global_load_lds)
            __builtin_amdgcn_global_load_lds(
                (const __attribute__((address_space(1))) unsigned int*)src,
                (__attribute__((address_space(3))) unsigned int*)dst, 16, 0, 0);
#else
            *(bf16x8*)dst = *(const bf16x8*)src;
#endif
        }
    };

    stageA(0, 0, 0);
    stageB(0, 0);
    __syncthreads();

    f32x4 acc[2][2];
#pragma unroll
    for (int i = 0; i < 2; ++i)
#pragma unroll
        for (int j = 0; j < 2; ++j) acc[i][j] = (f32x4)0.f;

    int bufA = 0, bufB = 0;
    for (int tap = 0; tap < 9; ++tap) {
#pragma unroll
        for (int ksub = 0; ksub < 4; ++ksub) {
            // prefetch next K-step (A) and next tap (B)
            if (ksub < 3) stageA(tap, ksub + 1, bufA ^ 1);
            else if (tap < 8) stageA(tap + 1, 0, bufA ^ 1);
            if (ksub == 0 && tap < 8) stageB(tap + 1, bufB ^ 1);

            __builtin_amdgcn_s_setprio(1);
#pragma unroll
            for (int ks2 = 0; ks2 < 2; ++ks2) {
#pragma unroll
                for (int ot = 0; ot < 2; ++ot) {
                    int r = ow * 32 + ot * 16 + (l & 15);
                    bf16x8 a = *(const bf16x8*)
                        &ldsA[bufA][(r << 6) + (((((l >> 4) + (ks2 << 2))) ^ (r & 7)) << 3)];
#pragma unroll
                    for (int pt = 0; pt < 2; ++pt) {
                        int F = pt * 8 + ksub * 2 + ks2;
                        bf16x8 bb = *(const bf16x8*)
                            &ldsB[bufB][(pxh << 13) + ((F * 64 + (l ^ (F & 7))) << 3)];
                        acc[ot][pt] = __builtin_amdgcn_mfma_f32_16x16x32_bf16(
                            a, bb, acc[ot][pt], 0, 0, 0);
                    }
                }
            }
            __builtin_amdgcn_s_setprio(0);
            __syncthreads();
            bufA ^= 1;
        }
        bufB ^= 1;
    }

    // epilogue: SiLU + store. D: row(o)=(l>>4)*4+j, col(px)=l&15
#pragma unroll
    for (int ot = 0; ot < 2; ++ot)
#pragma unroll
        for (int pt = 0; pt < 2; ++pt) {
            int px = pxh * 32 + pt * 16 + (l & 15);
#pragma unroll
            for (int j = 0; j < 4; ++j) {
                int o = ow * 32 + ot * 16 + (l >> 4) * 4 + j;
                float a = acc[ot][pt][j];
                out[((b * 256 + o) << 12) + hh * 64 + px] = a / (1.f + expf(-a));
            }
        }
}

// ---------------------------------------------------------------------------
// K3 fused fallback — used only if ws too small for samp.
__global__ __launch_bounds__(512, 4) void k3_dcn(const unsigned short* __restrict__ xph,
                                                 const float* __restrict__ off,
                                                 const unsigned short* __restrict__ wTb,
                                                 float* __restrict__ out) {
    __shared__ int   i00[288], i01[288], i10[288], i11[288];
    __shared__ float w00[288], w01[288], w10[288], w11[288];
    __shared__ unsigned short smp[2][16 * 64 * 8];
    int t = threadIdx.x;
    int orig = blockIdx.x;
    int bx = (orig & 7) * 64 + (orig >> 3);
    int b = bx >> 7, h = (bx >> 1) & 63, wh = (bx & 1) * 32;
    int wv = t >> 6, l = t & 63;
    const unsigned short* xb = xph + (b << 20);

    if (t < 288) {
        int n = t >> 5, p = t & 31;
        int w = wh + p;
        float oy = off[((b * 18 + n) << 12) + h * 64 + w];
        float ox = off[((b * 18 + n + 9) << 12) + h * 64 + w];
        float py = (float)(h + n / 3 - 1) + oy;
        float px = (float)(w + n % 3 - 1) + ox;
        py = fminf(fmaxf(py, 0.f), 63.f);
        px = fminf(fmaxf(px, 0.f), 63.f);
        float fy = floorf(py), fx = floorf(px);
        int y0 = (int)fy, x0 = (int)fx;
        float wy = py - fy, wx = px - fx;
        int y1 = min(y0 + 1, 63), x1 = min(x0 + 1, 63);
        i00[t] = (y0 * 64 + x0) << 8;  i01[t] = (y0 * 64 + x1) << 8;
        i10[t] = (y1 * 64 + x0) << 8;  i11[t] = (y1 * 64 + x1) << 8;
        w00[t] = (1.f - wy) * (1.f - wx);  w01[t] = (1.f - wy) * wx;
        w10[t] = wy * (1.f - wx);          w11[t] = wy * wx;
    }
    __syncthreads();

    int pt_p = wv & 1;
    int ks0 = wv >> 1;
    int px_p = pt_p * 16 + (l & 15);
    int cgl = l >> 4;
    bf16x8 g[2][4];

    auto stage_issue = [&](int tap) {
        int sb = tap * 32 + px_p;
        int a00 = i00[sb], a01 = i01[sb], a10 = i10[sb], a11 = i11[sb];
#pragma unroll
        for (int ku = 0; ku < 2; ++ku) {
            int ks = ks0 + ku * 4;
            int c = (ks * 4 + cgl) << 3;
            g[ku][0] = *(const bf16x8*)(xb + a00 + c);
            g[ku][1] = *(const bf16x8*)(xb + a01 + c);
            g[ku][2] = *(const bf16x8*)(xb + a10 + c);
            g[ku][3] = *(const bf16x8*)(xb + a11 + c);
        }
    };
    auto stage_write = [&](int tap) {
        int bu = tap & 1;
        int sb = tap * 32 + px_p;
        float b00 = w00[sb], b01 = w01[sb], b10 = w10[sb], b11 = w11[sb];
#pragma unroll
        for (int ku = 0; ku < 2; ++ku) {
            bf16x8 r;
#pragma unroll
            for (int j = 0; j < 8; ++j) {
                float v = b00 * b2f((unsigned short)g[ku][0][j]) +
                          b01 * b2f((unsigned short)g[ku][1][j]) +
                          b10 * b2f((unsigned short)g[ku][2][j]) +
                          b11 * b2f((unsigned short)g[ku][3][j]);
                r[j] = (short)f2b(v);
            }
            int F = pt_p * 8 + ks0 + ku * 4;
            *(bf16x8*)&smp[bu][(F * 64 + (l ^ (F & 7))) << 3] = r;
        }
    };

    stage_issue(0);
    __builtin_amdgcn_sched_barrier(0);
    stage_write(0);
    __syncthreads();

    f32x4 acc[2][2];
#pragma unroll
    for (int i = 0; i < 2; ++i)
#pragma unroll
        for (int j = 0; j < 2; ++j) acc[i][j] = (f32x4)0.f;

    int arow = l & 15, areg = l >> 4;
    for (int tap = 0; tap < 9; ++tap) {
        if (tap < 8) stage_issue(tap + 1);
        __builtin_amdgcn_sched_barrier(0);
        int bu = tap & 1;
        const unsigned short* wbase =
            wTb + (tap * 256 + wv * 32 + arow) * 256 + areg * 8;
        __builtin_amdgcn_s_setprio(1);
#pragma unroll
        for (int ks = 0; ks < 8; ++ks) {
            bf16x8 a0 = *(const bf16x8*)(wbase + ks * 32);
            bf16x8 a1 = *(const bf16x8*)(wbase + 16 * 256 + ks * 32);
#pragma unroll
            for (int pt = 0; pt < 2; ++pt) {
                int F = pt * 8 + ks;
                bf16x8 bfr = *(const bf16x8*)
                    &smp[bu][(F * 64 + (l ^ (F & 7))) << 3];
                acc[0][pt] = __builtin_amdgcn_mfma_f32_16x16x32_bf16(a0, bfr, acc[0][pt], 0, 0, 0);
                acc[1][pt] = __builtin_amdgcn_mfma_f32_16x16x32_bf16(a1, bfr, acc[1][pt], 0, 0, 0);
            }
        }
        __builtin_amdgcn_s_setprio(0);
        __builtin_amdgcn_sched_barrier(0);
        if (tap < 8) stage_write(tap + 1);
        __syncthreads();
    }

#pragma unroll
    for (int ot = 0; ot < 2; ++ot)
#pragma unroll
        for (int pt = 0; pt < 2; ++pt) {
            int px = wh + pt * 16 + (l & 15);
#pragma unroll
            for (int j = 0; j < 4; ++j) {
                int o = wv * 32 + ot * 16 + (l >> 4) * 4 + j;
                float a = acc[ot][pt][j];
                out[((b * 256 + o) << 12) + h * 64 + px] = a / (1.f + expf(-a));
            }
        }
}

// ---------------------------------------------------------------------------
extern "C" void kernel_launch(void* const* d_in, const int* in_sizes, int n_in,
                              void* d_out, int out_size, void* d_ws, size_t ws_size,
                              hipStream_t stream) {
    const float* x     = (const float*)d_in[0];
    const float* pw    = (const float*)d_in[1];
    const float* gamma = (const float*)d_in[2];
    const float* beta  = (const float*)d_in[3];
    const float* mean  = (const float*)d_in[4];
    const float* var   = (const float*)d_in[5];
    const float* offw  = (const float*)d_in[6];
    const float* offb  = (const float*)d_in[7];
    const float* dcn   = (const float*)d_in[8];
    float* ws = (float*)d_ws;
    float* xp   = ws + XP_F;
    float* off  = ws + OFF_F;
    unsigned short* xph = (unsigned short*)(ws + XPH_F);
    unsigned short* wTb = (unsigned short*)(ws + WTB_F);
    float* part = ws + PART_F;
    unsigned short* samp = (unsigned short*)(ws + SAMP_F);
    float* out = (float*)d_out;

    hipLaunchKernelGGL(k0_prep, dim3(2304), dim3(256), 0, stream, dcn, wTb);
    hipLaunchKernelGGL(k1_pw_bn, dim3(256, 4), dim3(256), 0, stream,
                       x, pw, gamma, beta, mean, var, xp, xph);
    hipLaunchKernelGGL(k2a_off, dim3(2048), dim3(256), 0, stream, xp, offw, part);
    hipLaunchKernelGGL(k2b_red, dim3(1152), dim3(256), 0, stream, part, offb, off);
    if (ws_size >= SPLIT_END_F * 4ULL) {
        hipLaunchKernelGGL(k3a_samp, dim3(4608), dim3(256), 0, stream, xph, off, samp);
        hipLaunchKernelGGL(k3b_gemm, dim3(256), dim3(1024), 0, stream, samp, wTb, out);
    } else {
        hipLaunchKernelGGL(k3_dcn, dim3(512), dim3(512), 0, stream, xph, off, wTb, out);
    }
}